// Round 8
// baseline (59.956 us; speedup 1.0000x reference)
//
#include <hip/hip_runtime.h>
#include <math.h>

#define NTOK 16384
#define D_   2048
#define E_   64
#define TPB  64            // tokens per block
#define NKC  (D_/32)       // 64 k32-steps

typedef _Float16 f16x8 __attribute__((ext_vector_type(8)));
typedef float    f32x4 __attribute__((ext_vector_type(4)));

#define LSCALE      256.0f          // pre-scale x and W before f16 split (denorm guard)
#define LSCALE2_INV (1.0f/65536.0f) // exact pow2 un-scale of acc

// LDS: 4 staging buffers of 16384 B at k*16384 (total 64 KB):
//   x  chunk 8192 B  ([64 rows][128 B], slot XOR-swizzled by row&7)
//   bh chunk 4096 B  at +8192  ([4 nt][1024 B], linear fragment order)
//   bl chunk 4096 B  at +12288
// After the K-loop the buffers are dead; logits [64][65] f32 + res [64][4]
// are aliased into the same space (no extra LDS -> 2 blocks/CU).
#define BUF_BYTES   16384
#define LOG_STRIDE  65
#define RES_OFF_F   (TPB*LOG_STRIDE)          // 4160 floats
#define SMEM_FLOATS 16384                     // 64 KB

// ---- Kernel 1: W (E x D fp32) -> fragment-ordered f16 hi/lo, scaled x256 ----
// Fragment order: element j of lane l for (n-tile nt, k32-step kc) is
//   W[e = nt*16 + (l&15)][k = kc*32 + (l>>4)*4 + (j&3) + (j>=4 ? 16 : 0)]
// Same k-map as the A operand -> any deviation from HW k-order cancels.
__global__ __launch_bounds__(256)
void prep_w(const float* __restrict__ W,
            _Float16* __restrict__ wh, _Float16* __restrict__ wl)
{
    const int idx = blockIdx.x * 256 + threadIdx.x;   // 0..16383
    const int l  = idx & 63;
    const int kc = (idx >> 6) & 63;
    const int nt = idx >> 12;                          // 0..3
    const int e  = nt * 16 + (l & 15);
    const int g  = l >> 4;
    const float* src = W + (size_t)e * D_ + kc * 32 + g * 4;
    const float4 f0 = *reinterpret_cast<const float4*>(src);
    const float4 f1 = *reinterpret_cast<const float4*>(src + 16);
    const float v[8] = {f0.x, f0.y, f0.z, f0.w, f1.x, f1.y, f1.z, f1.w};
    f16x8 h, lo;
#pragma unroll
    for (int j = 0; j < 8; ++j) {
        const float vs = v[j] * LSCALE;
        const _Float16 hj = (_Float16)vs;
        h[j]  = hj;
        lo[j] = (_Float16)(vs - (float)hj);
    }
    *reinterpret_cast<f16x8*>(wh + (size_t)idx * 8) = h;
    *reinterpret_cast<f16x8*>(wl + (size_t)idx * 8) = lo;
}

__device__ __forceinline__ void stage16(const void* g, void* l) {
    __builtin_amdgcn_global_load_lds(
        (const __attribute__((address_space(1))) void*)g,
        (__attribute__((address_space(3))) void*)l, 16, 0, 0);
}

// ---- Kernel 2: MFMA router, staged-LDS 4-deep async pipeline ----
// 256 blocks x 512 threads (8 waves, 64 tokens, 2 blocks/CU -> 16 waves/CU).
// Wave w: mt = w>>1 (16 tokens), np = w&1 (experts np*32..+31).
// Per kc: block stages x(8KB, once per 64 tokens) + bh/bl(8KB) via
// global_load_lds; counted s_waitcnt vmcnt(4) keeps 3 stages in flight.
// Per-output-tile fragment sequence + MFMA order bitwise-match rounds 5-7
// (frozen math: absmax 1.0 passes; do NOT reorder).
__global__ __launch_bounds__(512, 4)
void router_mfma(const float* __restrict__ x,
                 const _Float16* __restrict__ wh,
                 const _Float16* __restrict__ wl,
                 const float* __restrict__ bias,
                 float* __restrict__ out)
{
    __shared__ float smem[SMEM_FLOATS];
    char* sb = (char*)smem;

    const int tid = threadIdx.x;
    const int l   = tid & 63;
    const int w   = __builtin_amdgcn_readfirstlane(tid >> 6);  // 0..7
    const int mt  = w >> 1;               // 0..3
    const int nt0 = (w & 1) * 2;
    const int nt1 = nt0 + 1;
    const int T0  = blockIdx.x * TPB;
    const int g   = l >> 4;

    f32x4 acc0 = {0.f, 0.f, 0.f, 0.f};
    f32x4 acc1 = {0.f, 0.f, 0.f, 0.f};

    // staging: wave w feeds x rows 8w..8w+7 (8 lanes/row, XOR-swizzled slots)
    // and one B quarter: w<4 -> bh[nt=w], w>=4 -> bl[nt=w-4].
    const int srow  = (w << 3) + (l >> 3);
    const int sslot = (l & 7) ^ (srow & 7);
    const float* xsrc0 = x + (size_t)(T0 + srow) * D_ + sslot * 4;
    const int bnt = w & 3;
    const _Float16* bsrc0 =
        (w < 4 ? wh : wl) + ((size_t)bnt * NKC * 64 + l) * 8;
    const int xdst_off = (w << 10);                   // + lane*16 implicit
    const int bdst_off = (w < 4 ? 8192 : 12288) + (bnt << 10);

    auto STAGE = [&](int kc) {
        char* bb = sb + (kc & 3) * BUF_BYTES;
        stage16(xsrc0 + kc * 32,          bb + xdst_off);
        stage16(bsrc0 + (size_t)kc * 512, bb + bdst_off);
    };

    const int arow = mt * 16 + (l & 15);              // A-fragment token row
    const int r7   = arow & 7;
    const int xa_off = arow * 128 + ((g       ^ r7) << 4);
    const int xb_off = arow * 128 + (((4 + g) ^ r7) << 4);

    auto COMPUTE = [&](int kc) {
        const char* bb = sb + (kc & 3) * BUF_BYTES;
        const float4 xa = *reinterpret_cast<const float4*>(bb + xa_off);
        const float4 xb = *reinterpret_cast<const float4*>(bb + xb_off);
        const f16x8 bh0 = *reinterpret_cast<const f16x8*>(bb + 8192  + nt0 * 1024 + (l << 4));
        const f16x8 bl0 = *reinterpret_cast<const f16x8*>(bb + 12288 + nt0 * 1024 + (l << 4));
        const f16x8 bh1 = *reinterpret_cast<const f16x8*>(bb + 8192  + nt1 * 1024 + (l << 4));
        const f16x8 bl1 = *reinterpret_cast<const f16x8*>(bb + 12288 + nt1 * 1024 + (l << 4));
        const float av[8] = {xa.x, xa.y, xa.z, xa.w, xb.x, xb.y, xb.z, xb.w};
        f16x8 ah, al_;
#pragma unroll
        for (int j = 0; j < 8; ++j) {
            const float vs = av[j] * LSCALE;
            const _Float16 hj = (_Float16)vs;
            ah[j]  = hj;
            al_[j] = (_Float16)(vs - (float)hj);
        }
        acc0 = __builtin_amdgcn_mfma_f32_16x16x32_f16(ah,  bh0, acc0, 0, 0, 0);
        acc0 = __builtin_amdgcn_mfma_f32_16x16x32_f16(al_, bh0, acc0, 0, 0, 0);
        acc0 = __builtin_amdgcn_mfma_f32_16x16x32_f16(ah,  bl0, acc0, 0, 0, 0);
        acc1 = __builtin_amdgcn_mfma_f32_16x16x32_f16(ah,  bh1, acc1, 0, 0, 0);
        acc1 = __builtin_amdgcn_mfma_f32_16x16x32_f16(al_, bh1, acc1, 0, 0, 0);
        acc1 = __builtin_amdgcn_mfma_f32_16x16x32_f16(ah,  bl1, acc1, 0, 0, 0);
    };

    // ---- pipeline: 3 stages in flight (2 loads/thread each), counted vmcnt ----
    STAGE(0); STAGE(1); STAGE(2);
    for (int kc = 0; kc < NKC - 3; ++kc) {
        asm volatile("s_waitcnt vmcnt(4)" ::: "memory");   // buf[kc] ready
        __builtin_amdgcn_s_barrier();
        STAGE(kc + 3);        // overwrites buf[kc-1]: fully consumed pre-barrier
        COMPUTE(kc);
    }
    asm volatile("s_waitcnt vmcnt(4)" ::: "memory");
    __builtin_amdgcn_s_barrier();
    COMPUTE(NKC - 3);
    asm volatile("s_waitcnt vmcnt(2)" ::: "memory");
    __builtin_amdgcn_s_barrier();
    COMPUTE(NKC - 2);
    asm volatile("s_waitcnt vmcnt(0)" ::: "memory");
    __builtin_amdgcn_s_barrier();
    COMPUTE(NKC - 1);
    // all waves past COMPUTE(62) via the last barrier; COMPUTE(63) reads buf3
    // (bytes 48K..64K) only, so writing logits at bytes 0..17K is race-free.

    // ---- C tiles -> LDS logits. C layout: col = lane&15, row = (lane>>4)*4 + r ----
    {
        float* logits = smem;                    // aliases dead staging buffers
        const int row0 = mt * 16 + g * 4;
        const int c0   = nt0 * 16 + (l & 15);
        const int c1   = nt1 * 16 + (l & 15);
#pragma unroll
        for (int r = 0; r < 4; ++r) {
            logits[(row0 + r) * LOG_STRIDE + c0] = acc0[r] * LSCALE2_INV;
            logits[(row0 + r) * LOG_STRIDE + c1] = acc1[r] * LSCALE2_INV;
        }
    }
    __syncthreads();

    // ---- top-2 + 2-way softmax: thread t scans token t's 64 logits ----
    float* res = smem + RES_OFF_F;
    if (tid < TPB) {
        const float* lg = smem + tid * LOG_STRIDE;
        float m1 = -INFINITY, m2 = -INFINITY;
        int i1 = 0, i2 = 0;
        for (int e = 0; e < E_; ++e) {
            const float v = lg[e] + bias[e];
            if (v > m1)      { m2 = m1; i2 = i1; m1 = v; i1 = e; }
            else if (v > m2) { m2 = v;  i2 = e; }
        }
        const float ex  = expf(m2 - m1);
        const float den = 1.f + ex;
        res[tid*4+0] = 1.f / den;
        res[tid*4+1] = ex / den;
        res[tid*4+2] = (float)i1;
        res[tid*4+3] = (float)i2;
    }
    __syncthreads();

    // ---- coalesced output: probs (64 tokens x 64 experts) ----
    const size_t obase = (size_t)T0 * E_;
#pragma unroll
    for (int i = 0; i < (TPB * E_) / 512; ++i) {   // 8 iters
        const int f = i * 512 + tid;
        const int t = f >> 6;
        const int e = f & 63;
        const float p1 = res[t*4+0];
        const float p2 = res[t*4+1];
        const int   i1 = (int)res[t*4+2];
        const int   i2 = (int)res[t*4+3];
        float v = 0.f;
        if (e == i1)      v = p1;
        else if (e == i2) v = p2;
        out[obase + f] = v;
    }
    // ids as float values (whole d_out is read as float32)
    if (tid < TPB * 2) {
        out[(size_t)NTOK * E_ + (size_t)T0 * 2 + tid] =
            res[(tid >> 1) * 4 + 2 + (tid & 1)];
    }
}

extern "C" void kernel_launch(void* const* d_in, const int* in_sizes, int n_in,
                              void* d_out, int out_size, void* d_ws, size_t ws_size,
                              hipStream_t stream) {
    const float* x = (const float*)d_in[0];
    const float* W = (const float*)d_in[1];
    const float* b = (const float*)d_in[2];
    float* out     = (float*)d_out;
    _Float16* wh   = (_Float16*)d_ws;                       // 256 KB
    _Float16* wl   = wh + (size_t)4 * NKC * 64 * 8;         // +256 KB

    hipLaunchKernelGGL(prep_w, dim3(64), dim3(256), 0, stream, W, wh, wl);
    hipLaunchKernelGGL(router_mfma, dim3(NTOK / TPB), dim3(512), 0, stream,
                       x, wh, wl, b, out);
}

// Round 10
// 59.740 us; speedup vs baseline: 1.0036x; 1.0036x over previous
//
#include <hip/hip_runtime.h>
#include <math.h>

#define NTOK 16384
#define D_   2048
#define E_   64
#define TPB  32            // tokens per block
#define NKC  (D_/32)       // 64 k32-steps
#define NS   16            // supersteps of 4 kc

typedef _Float16 f16x8 __attribute__((ext_vector_type(8)));
typedef float    f32x4 __attribute__((ext_vector_type(4)));

#define LSCALE      256.0f          // pre-scale x and W before f16 split (denorm guard)
#define LSCALE2_INV (1.0f/65536.0f) // exact pow2 un-scale of acc

// LDS: 4 x-superstep buffers of 16384 B at (s%4)*16384 (total 64 KB).
// Buffer = 4 kc-pages of 4096 B ([32 rows][8 slots of 16 B], slot XOR-swizzled
// by row&7; source pre-swizzled, LDS linear, read swizzled).
// STAGE_X(s+3) at end of iter s overwrites buf[(s-1)%4]: consumed in iter s-1,
// two barriers before the write -> race-free (round 9's 2-buffer version
// overwrote the buffer being read -> corrupted ids).
// Epilogue logits [32][65] + res [32][4] alias buf0 (last read iter 12).
#define LOG_STRIDE  65
#define RES_OFF_F   (TPB*LOG_STRIDE)          // 2080 floats
#define SMEM_FLOATS 16384                     // 64 KB

// ---- Kernel 1: W (E x D fp32) -> fragment-ordered f16 hi/lo, scaled x256 ----
// Fragment order: element j of lane l for (n-tile nt, k32-step kc) is
//   W[e = nt*16 + (l&15)][k = kc*32 + (l>>4)*4 + (j&3) + (j>=4 ? 16 : 0)]
// Same k-map as the A operand -> any deviation from HW k-order cancels.
__global__ __launch_bounds__(256)
void prep_w(const float* __restrict__ W,
            _Float16* __restrict__ wh, _Float16* __restrict__ wl)
{
    const int idx = blockIdx.x * 256 + threadIdx.x;   // 0..16383
    const int l  = idx & 63;
    const int kc = (idx >> 6) & 63;
    const int nt = idx >> 12;                          // 0..3
    const int e  = nt * 16 + (l & 15);
    const int g  = l >> 4;
    const float* src = W + (size_t)e * D_ + kc * 32 + g * 4;
    const float4 f0 = *reinterpret_cast<const float4*>(src);
    const float4 f1 = *reinterpret_cast<const float4*>(src + 16);
    const float v[8] = {f0.x, f0.y, f0.z, f0.w, f1.x, f1.y, f1.z, f1.w};
    f16x8 h, lo;
#pragma unroll
    for (int j = 0; j < 8; ++j) {
        const float vs = v[j] * LSCALE;
        const _Float16 hj = (_Float16)vs;
        h[j]  = hj;
        lo[j] = (_Float16)(vs - (float)hj);
    }
    *reinterpret_cast<f16x8*>(wh + (size_t)idx * 8) = h;
    *reinterpret_cast<f16x8*>(wl + (size_t)idx * 8) = lo;
}

__device__ __forceinline__ void stage16(const void* g, void* l) {
    __builtin_amdgcn_global_load_lds(
        (const __attribute__((address_space(1))) void*)g,
        (__attribute__((address_space(3))) void*)l, 16, 0, 0);
}

// ---- Kernel 2: MFMA router ----
// 512 blocks x 512 threads (8 waves, 32 tokens, 2 blocks/CU -> 16 waves/CU).
// Wave w: mt = w>>2 (16 tokens), nt = w&3 (16 experts) -> one 16x16 C tile.
// Schedule per superstep s (4 kc):
//   1. issue B[s+1] global->reg (8x16B, L2-resident; one iter ahead of use,
//      issued BEFORE any newer x stage so B-consume vmcnt waits - which retire
//      the in-order queue - never stall on the newest x stages)
//   2. COMPUTE x4 from buf[s%4] with B[s] regs
//   3. STAGE_X(s+3) (2x16B global_load_lds)
//   4. rotate B regs; counted vmcnt(10); barrier    (16 barriers total)
// Per-C-tile MFMA chain (hh,lh,hl; kc ascending; same fragment maps) is
// bitwise-identical to rounds 5-8 (frozen math: absmax 1.0; do NOT reorder).
__global__ __launch_bounds__(512, 4)
void router_mfma(const float* __restrict__ x,
                 const _Float16* __restrict__ wh,
                 const _Float16* __restrict__ wl,
                 const float* __restrict__ bias,
                 float* __restrict__ out)
{
    __shared__ float smem[SMEM_FLOATS];
    char* sb = (char*)smem;

    const int tid = threadIdx.x;
    const int l   = tid & 63;
    const int w   = __builtin_amdgcn_readfirstlane(tid >> 6);  // 0..7
    const int mt  = w >> 2;               // 0..1
    const int nt  = w & 3;                // 0..3
    const int T0  = blockIdx.x * TPB;
    const int g   = l >> 4;

    f32x4 acc = {0.f, 0.f, 0.f, 0.f};

    // --- x staging: thread t feeds chunks c = t and c = 512+t of each 16 KB
    // superstep. chunk c: kcLo=c>>8, row=(c>>3)&31, pos=c&7, srcslot=pos^(row&7).
    const int c1   = 512 + tid;
    const int row0 = (tid >> 3) & 31, slot0 = (tid & 7) ^ (row0 & 7);
    const int row1 = (c1  >> 3) & 31, slot1 = (c1  & 7) ^ (row1 & 7);
    const float* xs0 = x + (size_t)(T0 + row0) * D_ + (tid >> 8) * 32 + slot0 * 4;
    const float* xs1 = x + (size_t)(T0 + row1) * D_ + (c1  >> 8) * 32 + slot1 * 4;

    auto STAGE_X = [&](int sup) {           // 2 x 16B global_load_lds
        const int bo = (sup & 3) << 14;
        stage16(xs0 + (size_t)sup * 128, sb + bo + (w << 10));          // HW adds lane*16
        stage16(xs1 + (size_t)sup * 128, sb + bo + 8192 + (w << 10));
    };

    // --- B fragment pointers (lane-contiguous 16 B, L2-resident ws) ---
    const _Float16* bh_base = wh + ((size_t)nt * NKC * 64 + l) * 8;
    const _Float16* bl_base = wl + ((size_t)nt * NKC * 64 + l) * 8;
    auto LDB_H = [&](int kc) { return *reinterpret_cast<const f16x8*>(bh_base + (size_t)kc * 512); };
    auto LDB_L = [&](int kc) { return *reinterpret_cast<const f16x8*>(bl_base + (size_t)kc * 512); };

    // --- LDS read offsets (match staging swizzle) ---
    const int arow   = mt * 16 + (l & 15);            // 0..31
    const int r7_    = arow & 7;
    const int xa_off = arow * 128 + ((g       ^ r7_) << 4);
    const int xb_off = arow * 128 + (((4 + g) ^ r7_) << 4);

    auto COMPUTE = [&](int pb, f16x8 bh, f16x8 bl) {
        const float4 xa = *reinterpret_cast<const float4*>(sb + pb + xa_off);
        const float4 xb = *reinterpret_cast<const float4*>(sb + pb + xb_off);
        f16x8 ah, al_;
        {
            float vs;
            vs = xa.x * LSCALE; ah[0] = (_Float16)vs; al_[0] = (_Float16)(vs - (float)ah[0]);
            vs = xa.y * LSCALE; ah[1] = (_Float16)vs; al_[1] = (_Float16)(vs - (float)ah[1]);
            vs = xa.z * LSCALE; ah[2] = (_Float16)vs; al_[2] = (_Float16)(vs - (float)ah[2]);
            vs = xa.w * LSCALE; ah[3] = (_Float16)vs; al_[3] = (_Float16)(vs - (float)ah[3]);
            vs = xb.x * LSCALE; ah[4] = (_Float16)vs; al_[4] = (_Float16)(vs - (float)ah[4]);
            vs = xb.y * LSCALE; ah[5] = (_Float16)vs; al_[5] = (_Float16)(vs - (float)ah[5]);
            vs = xb.z * LSCALE; ah[6] = (_Float16)vs; al_[6] = (_Float16)(vs - (float)ah[6]);
            vs = xb.w * LSCALE; ah[7] = (_Float16)vs; al_[7] = (_Float16)(vs - (float)ah[7]);
        }
        acc = __builtin_amdgcn_mfma_f32_16x16x32_f16(ah,  bh, acc, 0, 0, 0);
        acc = __builtin_amdgcn_mfma_f32_16x16x32_f16(al_, bh, acc, 0, 0, 0);
        acc = __builtin_amdgcn_mfma_f32_16x16x32_f16(ah,  bl, acc, 0, 0, 0);
    };

    // --- prologue: B[0] first (so its consume-wait never drains x0-x2),
    // then 3 x supersteps. queue: B:8, x0:2, x1:2, x2:2 -> vmcnt(4) = buf0 ready.
    f16x8 bhc[4], blc[4], bhn[4], bln[4];
#pragma unroll
    for (int j = 0; j < 4; ++j) { bhc[j] = LDB_H(j); blc[j] = LDB_L(j); }
    STAGE_X(0); STAGE_X(1); STAGE_X(2);
    asm volatile("s_waitcnt vmcnt(4)" ::: "memory");
    __builtin_amdgcn_s_barrier();

    for (int s = 0; s < NS; ++s) {
        const int K  = s << 2;
        const int bo = (s & 3) << 14;
        if (s < NS - 1) {
#pragma unroll
            for (int j = 0; j < 4; ++j) { bhn[j] = LDB_H(K + 4 + j); bln[j] = LDB_L(K + 4 + j); }
        }
        COMPUTE(bo,         bhc[0], blc[0]);
        COMPUTE(bo | 4096,  bhc[1], blc[1]);
        COMPUTE(bo | 8192,  bhc[2], blc[2]);
        COMPUTE(bo | 12288, bhc[3], blc[3]);
        if (s + 3 < NS) STAGE_X(s + 3);
        if (s < NS - 1) {
#pragma unroll
            for (int j = 0; j < 4; ++j) { bhc[j] = bhn[j]; blc[j] = bln[j]; }
            // steady state outstanding: B[s+1]:8 + x(s+3):2 = 10 (x(s+1) and
            // older already retired by the in-order B-consume waits above)
            asm volatile("s_waitcnt vmcnt(10)" ::: "memory");
            __builtin_amdgcn_s_barrier();
        }
    }

    // ---- C tile -> LDS logits (aliases buf0; s=15 computed from buf3) ----
    // C layout: col = lane&15, row = (lane>>4)*4 + r
    {
        float* logits = smem;
        const int rr0 = mt * 16 + g * 4;
        const int cc  = nt * 16 + (l & 15);
#pragma unroll
        for (int r = 0; r < 4; ++r)
            logits[(rr0 + r) * LOG_STRIDE + cc] = acc[r] * LSCALE2_INV;
    }
    __syncthreads();

    // ---- top-2 + 2-way softmax: thread t scans token t's 64 logits ----
    float* res = smem + RES_OFF_F;
    if (tid < TPB) {
        const float* lg = smem + tid * LOG_STRIDE;
        float m1 = -INFINITY, m2 = -INFINITY;
        int i1 = 0, i2 = 0;
        for (int e = 0; e < E_; ++e) {
            const float v = lg[e] + bias[e];
            if (v > m1)      { m2 = m1; i2 = i1; m1 = v; i1 = e; }
            else if (v > m2) { m2 = v;  i2 = e; }
        }
        const float ex  = expf(m2 - m1);
        const float den = 1.f + ex;
        res[tid*4+0] = 1.f / den;
        res[tid*4+1] = ex / den;
        res[tid*4+2] = (float)i1;
        res[tid*4+3] = (float)i2;
    }
    __syncthreads();

    // ---- coalesced output: probs (32 tokens x 64 experts) ----
    const size_t obase = (size_t)T0 * E_;
#pragma unroll
    for (int i = 0; i < (TPB * E_) / 512; ++i) {   // 4 iters
        const int f = i * 512 + tid;
        const int t = f >> 6;
        const int e = f & 63;
        const float p1 = res[t*4+0];
        const float p2 = res[t*4+1];
        const int   i1 = (int)res[t*4+2];
        const int   i2 = (int)res[t*4+3];
        float v = 0.f;
        if (e == i1)      v = p1;
        else if (e == i2) v = p2;
        out[obase + f] = v;
    }
    // ids as float values (whole d_out is read as float32)
    if (tid < TPB * 2) {
        out[(size_t)NTOK * E_ + (size_t)T0 * 2 + tid] =
            res[(tid >> 1) * 4 + 2 + (tid & 1)];
    }
}

extern "C" void kernel_launch(void* const* d_in, const int* in_sizes, int n_in,
                              void* d_out, int out_size, void* d_ws, size_t ws_size,
                              hipStream_t stream) {
    const float* x = (const float*)d_in[0];
    const float* W = (const float*)d_in[1];
    const float* b = (const float*)d_in[2];
    float* out     = (float*)d_out;
    _Float16* wh   = (_Float16*)d_ws;                       // 256 KB
    _Float16* wl   = wh + (size_t)4 * NKC * 64 * 8;         // +256 KB

    hipLaunchKernelGGL(prep_w, dim3(64), dim3(256), 0, stream, W, wh, wl);
    hipLaunchKernelGGL(router_mfma, dim3(NTOK / TPB), dim3(512), 0, stream,
                       x, wh, wl, b, out);
}

// Round 11
// 55.402 us; speedup vs baseline: 1.0822x; 1.0783x over previous
//
#include <hip/hip_runtime.h>
#include <math.h>

#define NTOK 16384
#define D_   2048
#define E_   64
#define TPB  16            // tokens per block
#define NKC  (D_/32)       // 64 k32-steps
#define NS   16            // supersteps of 4 kc

typedef _Float16 f16x8 __attribute__((ext_vector_type(8)));
typedef float    f32x4 __attribute__((ext_vector_type(4)));

#define LSCALE      256.0f          // pre-scale x and W before f16 split (denorm guard)
#define LSCALE2_INV (1.0f/65536.0f) // exact pow2 un-scale of acc

// LDS: 16-page x ring, page (kc&15) = 2048 B ([16 rows][8 slots of 16 B],
// slot XOR-swizzled by row&7; source pre-swizzled, LDS linear, read swizzled).
// Page kc is staged 2 supersteps ahead (distance 8 kc, ring 16 -> race-free).
// Epilogue logits [16][65] + res [16][4] alias pages 0-2 (not read after
// superstep 12; only pages 12-15 are read during the final superstep).
#define SMEM_FLOATS 8192           // 32 KB -> 4+ blocks/CU by LDS

// ---- Kernel 1: W (E x D fp32) -> fragment-ordered f16 hi/lo, scaled x256 ----
// Fragment order: element j of lane l for (n-tile nt, k32-step kc) is
//   W[e = nt*16 + (l&15)][k = kc*32 + (l>>4)*4 + (j&3) + (j>=4 ? 16 : 0)]
// Same k-map as the A operand -> any deviation from HW k-order cancels.
__global__ __launch_bounds__(256)
void prep_w(const float* __restrict__ W,
            _Float16* __restrict__ wh, _Float16* __restrict__ wl)
{
    const int idx = blockIdx.x * 256 + threadIdx.x;   // 0..16383
    const int l  = idx & 63;
    const int kc = (idx >> 6) & 63;
    const int nt = idx >> 12;                          // 0..3
    const int e  = nt * 16 + (l & 15);
    const int g  = l >> 4;
    const float* src = W + (size_t)e * D_ + kc * 32 + g * 4;
    const float4 f0 = *reinterpret_cast<const float4*>(src);
    const float4 f1 = *reinterpret_cast<const float4*>(src + 16);
    const float v[8] = {f0.x, f0.y, f0.z, f0.w, f1.x, f1.y, f1.z, f1.w};
    f16x8 h, lo;
#pragma unroll
    for (int j = 0; j < 8; ++j) {
        const float vs = v[j] * LSCALE;
        const _Float16 hj = (_Float16)vs;
        h[j]  = hj;
        lo[j] = (_Float16)(vs - (float)hj);
    }
    *reinterpret_cast<f16x8*>(wh + (size_t)idx * 8) = h;
    *reinterpret_cast<f16x8*>(wl + (size_t)idx * 8) = lo;
}

__device__ __forceinline__ void stage16(const void* g, void* l) {
    __builtin_amdgcn_global_load_lds(
        (const __attribute__((address_space(1))) void*)g,
        (__attribute__((address_space(3))) void*)l, 16, 0, 0);
}

// ---- Kernel 2: MFMA router, small-block / many-barrier-domain pipeline ----
// 1024 blocks x 256 threads (4 waves, 16 tokens) -> 4 blocks/CU: 4 INDEPENDENT
// barrier domains per CU (r7/r10 had 1-2; whole-CU convoys drained the load
// queue -> x stream stuck at ~2.3 TB/s). Wave w owns n-tile nt=w (16 experts),
// full K, single frozen acc chain. Per superstep s (4 kc):
//   issue B(s+1) (8x16B, L2) -> stage own ring page 4(s+2)+w (2x16B)
//   -> vmcnt(12) [retires B(s)] -> compute 4 kc -> vmcnt(10) [retires page
//   (s+1)] -> s_barrier.  x slack ~2 supersteps, B slack ~1 (in-order queue).
// Per-C-tile MFMA chain (hh,lh,hl; kc ascending; same fragment maps) is
// bitwise-identical to rounds 5-10 (frozen math: absmax 1.0; do NOT reorder).
__global__ __launch_bounds__(256, 4)
void router_mfma(const float* __restrict__ x,
                 const _Float16* __restrict__ wh,
                 const _Float16* __restrict__ wl,
                 const float* __restrict__ bias,
                 float* __restrict__ out)
{
    __shared__ float smem[SMEM_FLOATS];
    char* sb = (char*)smem;

    const int tid = threadIdx.x;
    const int l   = tid & 63;
    const int w   = __builtin_amdgcn_readfirstlane(tid >> 6);  // 0..3 = nt
    const int T0  = blockIdx.x * TPB;
    const int g   = l >> 4;

    f32x4 acc = {0.f, 0.f, 0.f, 0.f};

    // --- x staging sources: lane i feeds row i>>3 (+8 for 2nd instr), linear
    // slot i&7, source slot (i&7)^(row&7). (8+row)&7 == row&7 -> same ssl.
    const int srow = l >> 3;
    const int ssl  = (l & 7) ^ (srow & 7);
    const float* xsA = x + (size_t)(T0 + srow) * D_ + ssl * 4;
    const float* xsB = xsA + (size_t)8 * D_;

    auto STAGE = [&](int kcs) {            // stage page kcs (this wave's own)
        char* pg = sb + ((kcs & 15) << 11);
        stage16(xsA + (size_t)kcs * 32, pg);          // rows 0-7  (+lane*16)
        stage16(xsB + (size_t)kcs * 32, pg + 1024);   // rows 8-15
    };

    // --- B fragment base (own nt only; lane-contiguous 16 B, L2-resident) ---
    const _Float16* bh_base = wh + ((size_t)w * NKC * 64 + l) * 8;
    const _Float16* bl_base = wl + ((size_t)w * NKC * 64 + l) * 8;

    // --- LDS read offsets (match staging swizzle) ---
    const int arow   = l & 15;
    const int r7_    = arow & 7;
    const int xa_off = arow * 128 + ((g       ^ r7_) << 4);
    const int xb_off = arow * 128 + (((4 + g) ^ r7_) << 4);

    f16x8 BhC[4], BlC[4], BhN[4], BlN[4];

    // --- prologue: B(0) first, then pages for supersteps 0,1 (own pages) ---
#pragma unroll
    for (int j = 0; j < 4; ++j) {
        BhC[j] = *reinterpret_cast<const f16x8*>(bh_base + (size_t)j * 512);
        BlC[j] = *reinterpret_cast<const f16x8*>(bl_base + (size_t)j * 512);
    }
    STAGE(w); STAGE(4 + w);
    asm volatile("s_waitcnt vmcnt(4)" ::: "memory");   // B0 + page(s=0) ready
    __builtin_amdgcn_sched_barrier(0);
    __builtin_amdgcn_s_barrier();

    for (int s = 0; s < NS; ++s) {
        const int K = s << 2;
        if (s < NS - 1) {
#pragma unroll
            for (int j = 0; j < 4; ++j) {
                BhN[j] = *reinterpret_cast<const f16x8*>(bh_base + (size_t)(K + 4 + j) * 512);
                BlN[j] = *reinterpret_cast<const f16x8*>(bl_base + (size_t)(K + 4 + j) * 512);
            }
        }
        if (s < NS - 2) STAGE(((s + 2) << 2) + w);
        // pre-MFMA wait: retire B(s) (x pages keep their slack)
        if (s < NS - 2)      { asm volatile("s_waitcnt vmcnt(12)" ::: "memory"); }
        else if (s == NS - 2){ asm volatile("s_waitcnt vmcnt(10)" ::: "memory"); }
        else                 { asm volatile("s_waitcnt vmcnt(0)"  ::: "memory"); }
        __builtin_amdgcn_sched_barrier(0);

#pragma unroll
        for (int j = 0; j < 4; ++j) {
            const int kc = K + j;
            const char* pg = sb + ((kc & 15) << 11);
            const float4 xa = *reinterpret_cast<const float4*>(pg + xa_off);
            const float4 xb = *reinterpret_cast<const float4*>(pg + xb_off);
            f16x8 ah, al_;
            {
                float vs;
                vs = xa.x * LSCALE; ah[0] = (_Float16)vs; al_[0] = (_Float16)(vs - (float)ah[0]);
                vs = xa.y * LSCALE; ah[1] = (_Float16)vs; al_[1] = (_Float16)(vs - (float)ah[1]);
                vs = xa.z * LSCALE; ah[2] = (_Float16)vs; al_[2] = (_Float16)(vs - (float)ah[2]);
                vs = xa.w * LSCALE; ah[3] = (_Float16)vs; al_[3] = (_Float16)(vs - (float)ah[3]);
                vs = xb.x * LSCALE; ah[4] = (_Float16)vs; al_[4] = (_Float16)(vs - (float)ah[4]);
                vs = xb.y * LSCALE; ah[5] = (_Float16)vs; al_[5] = (_Float16)(vs - (float)ah[5]);
                vs = xb.z * LSCALE; ah[6] = (_Float16)vs; al_[6] = (_Float16)(vs - (float)ah[6]);
                vs = xb.w * LSCALE; ah[7] = (_Float16)vs; al_[7] = (_Float16)(vs - (float)ah[7]);
            }
            acc = __builtin_amdgcn_mfma_f32_16x16x32_f16(ah,  BhC[j], acc, 0, 0, 0);
            acc = __builtin_amdgcn_mfma_f32_16x16x32_f16(al_, BhC[j], acc, 0, 0, 0);
            acc = __builtin_amdgcn_mfma_f32_16x16x32_f16(ah,  BlC[j], acc, 0, 0, 0);
        }
#pragma unroll
        for (int j = 0; j < 4; ++j) { BhC[j] = BhN[j]; BlC[j] = BlN[j]; }

        if (s < NS - 2) {
            asm volatile("s_waitcnt vmcnt(10)" ::: "memory");  // page(s+1) ready
            __builtin_amdgcn_s_barrier();
        } else if (s == NS - 2) {
            asm volatile("s_waitcnt vmcnt(8)" ::: "memory");
            __builtin_amdgcn_s_barrier();
        }
    }

    // ---- C tile -> LDS logits (aliases pages 0-2; only pages 12-15 were
    // read in the final superstep -> no conflict). C layout: col = lane&15,
    // row = (lane>>4)*4 + r.
    {
        float* logits = smem;
        const int rr0 = g * 4;
        const int cc  = w * 16 + (l & 15);
#pragma unroll
        for (int r = 0; r < 4; ++r)
            logits[(rr0 + r) * 65 + cc] = acc[r] * LSCALE2_INV;
    }
    __syncthreads();

    // ---- top-2 + 2-way softmax: thread t scans token t's 64 logits ----
    float* res = smem + TPB * 65;          // [16][4]: p1, p2, i1, i2
    if (tid < TPB) {
        const float* lg = smem + tid * 65;
        float m1 = -INFINITY, m2 = -INFINITY;
        int i1 = 0, i2 = 0;
        for (int e = 0; e < E_; ++e) {
            const float v = lg[e] + bias[e];
            if (v > m1)      { m2 = m1; i2 = i1; m1 = v; i1 = e; }
            else if (v > m2) { m2 = v;  i2 = e; }
        }
        const float ex  = expf(m2 - m1);
        const float den = 1.f + ex;
        res[tid*4+0] = 1.f / den;
        res[tid*4+1] = ex / den;
        res[tid*4+2] = (float)i1;
        res[tid*4+3] = (float)i2;
    }
    __syncthreads();

    // ---- coalesced output: probs (16 tokens x 64 experts = 1024 floats) ----
    const size_t obase = (size_t)T0 * E_;
#pragma unroll
    for (int i = 0; i < (TPB * E_) / 256; ++i) {   // 4 iters
        const int f = i * 256 + tid;
        const int t = f >> 6;
        const int e = f & 63;
        const float p1 = res[t*4+0];
        const float p2 = res[t*4+1];
        const int   i1 = (int)res[t*4+2];
        const int   i2 = (int)res[t*4+3];
        float v = 0.f;
        if (e == i1)      v = p1;
        else if (e == i2) v = p2;
        out[obase + f] = v;
    }
    // ids as float values (whole d_out is read as float32)
    if (tid < TPB * 2) {
        out[(size_t)NTOK * E_ + (size_t)T0 * 2 + tid] =
            res[(tid >> 1) * 4 + 2 + (tid & 1)];
    }
}

extern "C" void kernel_launch(void* const* d_in, const int* in_sizes, int n_in,
                              void* d_out, int out_size, void* d_ws, size_t ws_size,
                              hipStream_t stream) {
    const float* x = (const float*)d_in[0];
    const float* W = (const float*)d_in[1];
    const float* b = (const float*)d_in[2];
    float* out     = (float*)d_out;
    _Float16* wh   = (_Float16*)d_ws;                       // 256 KB
    _Float16* wl   = wh + (size_t)4 * NKC * 64 * 8;         // +256 KB

    hipLaunchKernelGGL(prep_w, dim3(64), dim3(256), 0, stream, W, wh, wl);
    hipLaunchKernelGGL(router_mfma, dim3(NTOK / TPB), dim3(256), 0, stream,
                       x, wh, wl, b, out);
}

// Round 12
// 51.604 us; speedup vs baseline: 1.1618x; 1.0736x over previous
//
#include <hip/hip_runtime.h>
#include <math.h>

#define NTOK 16384
#define D_   2048
#define E_   64
#define TPB  16            // tokens per block (= per wave)
#define NKC  (D_/32)       // 64 k32-steps

typedef _Float16 f16x8 __attribute__((ext_vector_type(8)));
typedef float    f32x4 __attribute__((ext_vector_type(4)));

#define LSCALE      256.0f          // pre-scale x and W before f16 split (denorm guard)
#define LSCALE2_INV (1.0f/65536.0f) // exact pow2 un-scale of acc

// ---- Kernel 1: W (E x D fp32) -> fragment-ordered f16 hi/lo, scaled x256 ----
// Fragment order: element j of lane l for (n-tile nt, k32-step kc) is
//   W[e = nt*16 + (l&15)][k = kc*32 + (l>>4)*4 + (j&3) + (j>=4 ? 16 : 0)]
// Same k-map as the A operand -> any deviation from HW k-order cancels.
__global__ __launch_bounds__(256)
void prep_w(const float* __restrict__ W,
            _Float16* __restrict__ wh, _Float16* __restrict__ wl)
{
    const int idx = blockIdx.x * 256 + threadIdx.x;   // 0..16383
    const int l  = idx & 63;
    const int kc = (idx >> 6) & 63;
    const int nt = idx >> 12;                          // 0..3
    const int e  = nt * 16 + (l & 15);
    const int g  = l >> 4;
    const float* src = W + (size_t)e * D_ + kc * 32 + g * 4;
    const float4 f0 = *reinterpret_cast<const float4*>(src);
    const float4 f1 = *reinterpret_cast<const float4*>(src + 16);
    const float v[8] = {f0.x, f0.y, f0.z, f0.w, f1.x, f1.y, f1.z, f1.w};
    f16x8 h, lo;
#pragma unroll
    for (int j = 0; j < 8; ++j) {
        const float vs = v[j] * LSCALE;
        const _Float16 hj = (_Float16)vs;
        h[j]  = hj;
        lo[j] = (_Float16)(vs - (float)hj);
    }
    *reinterpret_cast<f16x8*>(wh + (size_t)idx * 8) = h;
    *reinterpret_cast<f16x8*>(wl + (size_t)idx * 8) = lo;
}

// ---- Kernel 2: MFMA router, single-wave blocks, ZERO barriers/LDS in K-loop ----
// 1024 blocks x 64 threads (1 wave = 16 tokens x ALL 64 experts, 4 acc tiles).
// All operands global->reg: A gather (16 rows x 64B lines, every byte used
// once), B fragments lane-contiguous 1KB/instr from L2-resident ws.
// 4-kc-deep register ring for BOTH A and B (depth-4 slack >> HBM latency at
// 1 wave/SIMD issue rate); no vmcnt asm, no s_barrier - the compiler inserts
// precise counted waits, and with no barriers there are no convoy drains.
// VGPR ~220 (fine: grid gives 1 wave/SIMD, budget 512).
// Per-C-tile MFMA chain (hh,lh,hl; kc ascending; same cvt, same fragment
// maps) is bitwise-identical to rounds 5-11 (absmax 1.0; do NOT reorder).
__global__ __launch_bounds__(64, 1)
void router_mfma(const float* __restrict__ x,
                 const _Float16* __restrict__ wh,
                 const _Float16* __restrict__ wl,
                 const float* __restrict__ bias,
                 float* __restrict__ out)
{
    __shared__ float smem[TPB * 65 + TPB * 4];   // logits [16][65] + res [16][4]

    const int l  = threadIdx.x;                  // 0..63, one wave
    const int T0 = blockIdx.x * TPB;
    const int g  = l >> 4;

    const float* xp = x + (size_t)(T0 + (l & 15)) * D_ + g * 4;
    const _Float16* bh_b = wh + (size_t)l * 8;   // + nt*32768 + kc*512
    const _Float16* bl_b = wl + (size_t)l * 8;

    f32x4 acc0 = {0.f,0.f,0.f,0.f}, acc1 = {0.f,0.f,0.f,0.f};
    f32x4 acc2 = {0.f,0.f,0.f,0.f}, acc3 = {0.f,0.f,0.f,0.f};

    float4 xa[4], xb[4];          // x ring, slot = kc&3 (constant after unroll)
    f16x8  BH[4][4], BL[4][4];    // B ring, [slot][nt]

    // prologue: fill depth-4 ring (kc = 0..3)
#pragma unroll
    for (int j = 0; j < 4; ++j) {
        xa[j] = *reinterpret_cast<const float4*>(xp + j * 32);
        xb[j] = *reinterpret_cast<const float4*>(xp + j * 32 + 16);
#pragma unroll
        for (int nt = 0; nt < 4; ++nt) {
            BH[j][nt] = *reinterpret_cast<const f16x8*>(bh_b + nt * 32768 + j * 512);
            BL[j][nt] = *reinterpret_cast<const f16x8*>(bl_b + nt * 32768 + j * 512);
        }
    }

    for (int s = 0; s < 16; ++s) {
        const int K = s << 2;
#pragma unroll
        for (int j = 0; j < 4; ++j) {
            // cvt (frozen math)
            f16x8 ah, al_;
            {
                float vs;
                vs = xa[j].x * LSCALE; ah[0] = (_Float16)vs; al_[0] = (_Float16)(vs - (float)ah[0]);
                vs = xa[j].y * LSCALE; ah[1] = (_Float16)vs; al_[1] = (_Float16)(vs - (float)ah[1]);
                vs = xa[j].z * LSCALE; ah[2] = (_Float16)vs; al_[2] = (_Float16)(vs - (float)ah[2]);
                vs = xa[j].w * LSCALE; ah[3] = (_Float16)vs; al_[3] = (_Float16)(vs - (float)ah[3]);
                vs = xb[j].x * LSCALE; ah[4] = (_Float16)vs; al_[4] = (_Float16)(vs - (float)ah[4]);
                vs = xb[j].y * LSCALE; ah[5] = (_Float16)vs; al_[5] = (_Float16)(vs - (float)ah[5]);
                vs = xb[j].z * LSCALE; ah[6] = (_Float16)vs; al_[6] = (_Float16)(vs - (float)ah[6]);
                vs = xb[j].w * LSCALE; ah[7] = (_Float16)vs; al_[7] = (_Float16)(vs - (float)ah[7]);
            }
            // 12 MFMA: per-tile chain hh, lh, hl (frozen)
            acc0 = __builtin_amdgcn_mfma_f32_16x16x32_f16(ah,  BH[j][0], acc0, 0, 0, 0);
            acc0 = __builtin_amdgcn_mfma_f32_16x16x32_f16(al_, BH[j][0], acc0, 0, 0, 0);
            acc0 = __builtin_amdgcn_mfma_f32_16x16x32_f16(ah,  BL[j][0], acc0, 0, 0, 0);
            acc1 = __builtin_amdgcn_mfma_f32_16x16x32_f16(ah,  BH[j][1], acc1, 0, 0, 0);
            acc1 = __builtin_amdgcn_mfma_f32_16x16x32_f16(al_, BH[j][1], acc1, 0, 0, 0);
            acc1 = __builtin_amdgcn_mfma_f32_16x16x32_f16(ah,  BL[j][1], acc1, 0, 0, 0);
            acc2 = __builtin_amdgcn_mfma_f32_16x16x32_f16(ah,  BH[j][2], acc2, 0, 0, 0);
            acc2 = __builtin_amdgcn_mfma_f32_16x16x32_f16(al_, BH[j][2], acc2, 0, 0, 0);
            acc2 = __builtin_amdgcn_mfma_f32_16x16x32_f16(ah,  BL[j][2], acc2, 0, 0, 0);
            acc3 = __builtin_amdgcn_mfma_f32_16x16x32_f16(ah,  BH[j][3], acc3, 0, 0, 0);
            acc3 = __builtin_amdgcn_mfma_f32_16x16x32_f16(al_, BH[j][3], acc3, 0, 0, 0);
            acc3 = __builtin_amdgcn_mfma_f32_16x16x32_f16(ah,  BL[j][3], acc3, 0, 0, 0);
            // prefetch kc+4 into the slot just consumed (depth-4 ring)
            if (s < 15) {
                const int kn = K + j + 4;
                xa[j] = *reinterpret_cast<const float4*>(xp + kn * 32);
                xb[j] = *reinterpret_cast<const float4*>(xp + kn * 32 + 16);
#pragma unroll
                for (int nt = 0; nt < 4; ++nt) {
                    BH[j][nt] = *reinterpret_cast<const f16x8*>(bh_b + nt * 32768 + (size_t)kn * 512);
                    BL[j][nt] = *reinterpret_cast<const f16x8*>(bl_b + nt * 32768 + (size_t)kn * 512);
                }
            }
        }
    }

    // ---- C tiles -> LDS logits. C layout: col = lane&15, row = (lane>>4)*4+r ----
    {
        const int col = l & 15;
#pragma unroll
        for (int r = 0; r < 4; ++r) {
            const int t = g * 4 + r;
            smem[t * 65 + 0  + col] = acc0[r] * LSCALE2_INV;
            smem[t * 65 + 16 + col] = acc1[r] * LSCALE2_INV;
            smem[t * 65 + 32 + col] = acc2[r] * LSCALE2_INV;
            smem[t * 65 + 48 + col] = acc3[r] * LSCALE2_INV;
        }
    }
    __syncthreads();   // single wave: effectively just an LDS drain

    // ---- top-2 + 2-way softmax (frozen scan): lane t handles token t ----
    float* res = smem + TPB * 65;
    if (l < TPB) {
        const float* lg = smem + l * 65;
        float m1 = -INFINITY, m2 = -INFINITY;
        int i1 = 0, i2 = 0;
        for (int e = 0; e < E_; ++e) {
            const float v = lg[e] + bias[e];
            if (v > m1)      { m2 = m1; i2 = i1; m1 = v; i1 = e; }
            else if (v > m2) { m2 = v;  i2 = e; }
        }
        const float ex  = expf(m2 - m1);
        const float den = 1.f + ex;
        res[l*4+0] = 1.f / den;
        res[l*4+1] = ex / den;
        res[l*4+2] = (float)i1;
        res[l*4+3] = (float)i2;
    }
    __syncthreads();

    // ---- output: probs (16 tokens x 64 experts = 1024 floats), float4 ----
    float* ob = out + (size_t)T0 * E_;
#pragma unroll
    for (int i = 0; i < 4; ++i) {
        const int idx = i * 256 + l * 4;
        const int t   = idx >> 6;
        const int e0  = idx & 63;
        const float p1 = res[t*4+0];
        const float p2 = res[t*4+1];
        const int   i1 = (int)res[t*4+2];
        const int   i2 = (int)res[t*4+3];
        float4 v;
        v.x = (e0+0 == i1) ? p1 : ((e0+0 == i2) ? p2 : 0.f);
        v.y = (e0+1 == i1) ? p1 : ((e0+1 == i2) ? p2 : 0.f);
        v.z = (e0+2 == i1) ? p1 : ((e0+2 == i2) ? p2 : 0.f);
        v.w = (e0+3 == i1) ? p1 : ((e0+3 == i2) ? p2 : 0.f);
        *reinterpret_cast<float4*>(ob + idx) = v;
    }
    // ids as float values (whole d_out is read as float32)
    if (l < TPB * 2) {
        out[(size_t)NTOK * E_ + (size_t)T0 * 2 + l] =
            res[(l >> 1) * 4 + 2 + (l & 1)];
    }
}

extern "C" void kernel_launch(void* const* d_in, const int* in_sizes, int n_in,
                              void* d_out, int out_size, void* d_ws, size_t ws_size,
                              hipStream_t stream) {
    const float* x = (const float*)d_in[0];
    const float* W = (const float*)d_in[1];
    const float* b = (const float*)d_in[2];
    float* out     = (float*)d_out;
    _Float16* wh   = (_Float16*)d_ws;                       // 256 KB
    _Float16* wl   = wh + (size_t)4 * NKC * 64 * 8;         // +256 KB

    hipLaunchKernelGGL(prep_w, dim3(64), dim3(256), 0, stream, W, wh, wl);
    hipLaunchKernelGGL(router_mfma, dim3(NTOK / TPB), dim3(64), 0, stream,
                       x, wh, wl, b, out);
}